// Round 4
// baseline (196.431 us; speedup 1.0000x reference)
//
#include <hip/hip_runtime.h>
#include <hip/hip_bf16.h>

typedef float vf4 __attribute__((ext_vector_type(4)));

// Problem constants (SelfAttention decode step)
#define B_    32
#define DIM_  4096
#define TSEQ  2048
#define LASTT 2047
#define NCH   8
#define CHUNK 256            // TSEQ / NCH
#define SCL   0.08838834764831845f   // 1/sqrt(128)
#define KCH   256            // 4096 / 16 K-chunks

__device__ __forceinline__ float dotv(vf4 a, vf4 b) {
    return fmaf(a[0], b[0], fmaf(a[1], b[1], fmaf(a[2], b[2], a[3] * b[3])));
}

// ---------------------------------------------------------------------------
// Shared GEMM body: tile = 128 rows x 32 batches, K-chunk = 256 (4 BK=64
// tiles). Per-thread 4x4 micro-tile (rows rg+32i, batches bg+8j). LDS layouts
// audited conflict-free. Result stays in c[][]; caller does the epilogue.
// W loads nontemporal (each line read exactly once across the grid).
// ---------------------------------------------------------------------------
__device__ __forceinline__ void gemm_tile(
    const float* __restrict__ W, const float* __restrict__ X,
    int kb0, float c[4][4]) {
    __shared__ __align__(16) vf4 wS[128][17];
    __shared__ __align__(16) vf4 xS[16][33];
    const int tid = threadIdx.x;
    const int rg = tid >> 3, bg = tid & 7;       // compute mapping
    const int sr4 = tid >> 4, swf = tid & 15;    // W staging mapping
    const int sb = tid >> 3, sxf = tid & 7;      // X staging mapping

    for (int tile = 0; tile < 4; ++tile) {
        const int kb4 = (kb0 + tile * 64) >> 2;     // float4 index base
        #pragma unroll
        for (int jj = 0; jj < 8; ++jj) {            // stage W: 128 rows x 16 f4
            const int row = sr4 + 16 * jj;
            wS[row][swf] = __builtin_nontemporal_load(
                ((const vf4*)(W + (size_t)row * DIM_)) + kb4 + swf);
        }
        #pragma unroll
        for (int jj = 0; jj < 2; ++jj) {            // stage X: 32 b x 16 f4
            const int f4i = sxf + 8 * jj;
            xS[f4i][sb] = ((const vf4*)(X + (size_t)sb * DIM_))[kb4 + f4i];
        }
        __syncthreads();
        #pragma unroll
        for (int k4 = 0; k4 < 16; ++k4) {
            const vf4 w0 = wS[rg      ][k4];
            const vf4 w1 = wS[rg + 32 ][k4];
            const vf4 w2 = wS[rg + 64 ][k4];
            const vf4 w3 = wS[rg + 96 ][k4];
            const vf4 x0 = xS[k4][bg     ];
            const vf4 x1 = xS[k4][bg + 8 ];
            const vf4 x2 = xS[k4][bg + 16];
            const vf4 x3 = xS[k4][bg + 24];
            #pragma unroll
            for (int cm = 0; cm < 4; ++cm) {
                c[0][0] = fmaf(w0[cm], x0[cm], c[0][0]);
                c[0][1] = fmaf(w0[cm], x1[cm], c[0][1]);
                c[0][2] = fmaf(w0[cm], x2[cm], c[0][2]);
                c[0][3] = fmaf(w0[cm], x3[cm], c[0][3]);
                c[1][0] = fmaf(w1[cm], x0[cm], c[1][0]);
                c[1][1] = fmaf(w1[cm], x1[cm], c[1][1]);
                c[1][2] = fmaf(w1[cm], x2[cm], c[1][2]);
                c[1][3] = fmaf(w1[cm], x3[cm], c[1][3]);
                c[2][0] = fmaf(w2[cm], x0[cm], c[2][0]);
                c[2][1] = fmaf(w2[cm], x1[cm], c[2][1]);
                c[2][2] = fmaf(w2[cm], x2[cm], c[2][2]);
                c[2][3] = fmaf(w2[cm], x3[cm], c[2][3]);
                c[3][0] = fmaf(w3[cm], x0[cm], c[3][0]);
                c[3][1] = fmaf(w3[cm], x1[cm], c[3][1]);
                c[3][2] = fmaf(w3[cm], x2[cm], c[3][2]);
                c[3][3] = fmaf(w3[cm], x3[cm], c[3][3]);
            }
        }
        __syncthreads();
    }
}

// ---------------------------------------------------------------------------
// K1: QKV projection + RoPE + atomicAdd scatter. RoPE is linear in (e,o), so
// it commutes with the split-K sum: each block rotates its own partial and
// atomically accumulates into (pre-zeroed) q_ws/k_ws/v_ws. Row pair (2m,2m+1)
// lives in lanes tid and tid^8 (rg parity) -> shfl_xor(.,8) pairing.
// Grid = 48 rowblocks x 16 K-chunks = 768.
// ---------------------------------------------------------------------------
__global__ __launch_bounds__(256) void k1_qkv(
    const float* __restrict__ x,  const float* __restrict__ wq,
    const float* __restrict__ wk, const float* __restrict__ wv,
    const float* __restrict__ fcos, const float* __restrict__ fsin,
    float* __restrict__ q_ws, float* __restrict__ k_ws, float* __restrict__ v_ws) {
    const int rb = blockIdx.x >> 4, kc = blockIdx.x & 15;
    const int rbase = rb * 128;
    const float* W; int rloc, kind;
    if (rbase < 4096)      { W = wq; rloc = rbase;        kind = 0; }
    else if (rbase < 5120) { W = wk; rloc = rbase - 4096; kind = 1; }
    else                   { W = wv; rloc = rbase - 5120; kind = 2; }
    float c[4][4] = {};
    gemm_tile(W + (size_t)rloc * DIM_, x, kc * KCH, c);

    const int tid = threadIdx.x;
    const int rg = tid >> 3, bg = tid & 7;
    float* dst = (kind == 0) ? q_ws : (kind == 1 ? k_ws : v_ws);
    const int stride = (kind == 0) ? 4096 : 1024;
    #pragma unroll
    for (int i = 0; i < 4; ++i) {
        const int row = rloc + rg + 32 * i;
        float vals[4];
        #pragma unroll
        for (int j = 0; j < 4; ++j) vals[j] = c[i][j];
        if (kind <= 1) {
            const int pi = (row & 126) >> 1;     // pair index, same for e/o lane
            const float cj = fcos[pi], sj = fsin[pi];
            #pragma unroll
            for (int j = 0; j < 4; ++j) {
                const float partner = __shfl_xor(vals[j], 8);
                float v = ((rg & 1) == 0) ? (vals[j] * cj - partner * sj)
                                          : (partner * sj + vals[j] * cj);
                if (kind == 0) v *= SCL;
                vals[j] = v;
            }
        }
        #pragma unroll
        for (int j = 0; j < 4; ++j)
            atomicAdd(&dst[(size_t)(bg + 8 * j) * stride + row], vals[j]);
    }
}

// ---------------------------------------------------------------------------
// K2: flash attention partials. Block = (b, g, chunk of 256). 4 waves x 64
// positions. Scores: 8 lanes/position, 2-deep prefetch, nontemporal K loads.
// PV group 0 is prefetched BEFORE the softmax phase (V latency hides under
// softmax), then a 2-deep pipeline. Position 2047 from k_ws/v_ws.
// ---------------------------------------------------------------------------
__global__ __launch_bounds__(256) void k2_attn(
    const float* __restrict__ q_ws, const float* __restrict__ k_ws,
    const float* __restrict__ v_ws, const float* __restrict__ cK,
    const float* __restrict__ cV,   float* __restrict__ cws) {
    __shared__ __align__(16) float p_lds[4][260];
    __shared__ __align__(16) float pacc[4][4][128];
    __shared__ float wred[4][4];
    __shared__ float wsum[4][4];
    const int blk = blockIdx.x;
    const int b = blk >> 6, g = (blk >> 3) & 7, c = blk & 7;
    const int tid = threadIdx.x, wave = tid >> 6, lane = tid & 63;
    const int tbase = c * CHUNK + wave * 64;
    const int s = lane & 7, pown = lane >> 3;

    const vf4* qb4 = (const vf4*)(q_ws + ((size_t)b * 32 + g * 4) * 128);
    vf4 q4[4][4];
    #pragma unroll
    for (int r = 0; r < 4; ++r)
        #pragma unroll
        for (int j = 0; j < 4; ++j)
            q4[r][j] = qb4[r * 32 + j * 8 + s];

    const vf4* kwsrow = (const vf4*)(k_ws + ((size_t)b * 8 + g) * 128);
    const vf4* vwsrow = (const vf4*)(v_ws + ((size_t)b * 8 + g) * 128);

    // ---- score phase (2-deep software pipeline) ----
    vf4 kb[4];
    {
        const int t = tbase + pown;
        const vf4* kr = (t == LASTT) ? kwsrow
            : (const vf4*)(cK + (((size_t)b * TSEQ + t) * 8 + g) * 128);
        #pragma unroll
        for (int j = 0; j < 4; ++j)
            kb[j] = __builtin_nontemporal_load(&kr[j * 8 + s]);
    }
    #pragma unroll
    for (int pg = 0; pg < 8; ++pg) {
        vf4 kn[4];
        if (pg < 7) {
            const int t = tbase + (pg + 1) * 8 + pown;
            const vf4* kr = (t == LASTT) ? kwsrow
                : (const vf4*)(cK + (((size_t)b * TSEQ + t) * 8 + g) * 128);
            #pragma unroll
            for (int j = 0; j < 4; ++j)
                kn[j] = __builtin_nontemporal_load(&kr[j * 8 + s]);
        }
        float a0 = 0.f, a1 = 0.f, a2 = 0.f, a3 = 0.f;
        #pragma unroll
        for (int j = 0; j < 4; ++j) {
            a0 += dotv(q4[0][j], kb[j]);
            a1 += dotv(q4[1][j], kb[j]);
            a2 += dotv(q4[2][j], kb[j]);
            a3 += dotv(q4[3][j], kb[j]);
        }
        #pragma unroll
        for (int m = 4; m >= 1; m >>= 1) {
            a0 += __shfl_xor(a0, m); a1 += __shfl_xor(a1, m);
            a2 += __shfl_xor(a2, m); a3 += __shfl_xor(a3, m);
        }
        const int idx = wave * 64 + pg * 8 + pown;
        if (s == 0) p_lds[0][idx] = a0;
        if (s == 1) p_lds[1][idx] = a1;
        if (s == 2) p_lds[2][idx] = a2;
        if (s == 3) p_lds[3][idx] = a3;
        #pragma unroll
        for (int j = 0; j < 4; ++j) kb[j] = kn[j];
    }

    // ---- early PV prefetch (group 0) -- hides V latency under softmax ----
    const int h = lane >> 5, col = lane & 31;
    vf4 vb[4];
    #pragma unroll
    for (int u = 0; u < 4; ++u) {
        const int t = tbase + u * 2 + h;
        const vf4* vp = (t == LASTT) ? vwsrow
            : (const vf4*)(cV + (((size_t)b * TSEQ + t) * 8 + g) * 128);
        vb[u] = __builtin_nontemporal_load(&vp[col]);
    }

    // ---- softmax (wave covers its own 64 positions) ----
    float sc[4];
    #pragma unroll
    for (int r = 0; r < 4; ++r) sc[r] = p_lds[r][wave * 64 + lane];
    #pragma unroll
    for (int r = 0; r < 4; ++r) {
        float m = sc[r];
        #pragma unroll
        for (int msk = 32; msk >= 1; msk >>= 1) m = fmaxf(m, __shfl_xor(m, msk));
        if (lane == 0) wred[wave][r] = m;
    }
    __syncthreads();
    float M[4], S[4];
    #pragma unroll
    for (int r = 0; r < 4; ++r)
        M[r] = fmaxf(fmaxf(wred[0][r], wred[1][r]), fmaxf(wred[2][r], wred[3][r]));
    #pragma unroll
    for (int r = 0; r < 4; ++r) {
        const float p = __expf(sc[r] - M[r]);
        p_lds[r][wave * 64 + lane] = p;
        float su = p;
        #pragma unroll
        for (int msk = 32; msk >= 1; msk >>= 1) su += __shfl_xor(su, msk);
        if (lane == 0) wsum[wave][r] = su;
    }
    __syncthreads();
    #pragma unroll
    for (int r = 0; r < 4; ++r)
        S[r] = wsum[0][r] + wsum[1][r] + wsum[2][r] + wsum[3][r];

    // ---- PV phase (2-deep pipeline) ----
    float a[4][4] = {};
    #pragma unroll
    for (int tt = 0; tt < 8; ++tt) {
        vf4 vn[4];
        if (tt < 7) {
            #pragma unroll
            for (int u = 0; u < 4; ++u) {
                const int t = tbase + (tt + 1) * 8 + u * 2 + h;
                const vf4* vp = (t == LASTT) ? vwsrow
                    : (const vf4*)(cV + (((size_t)b * TSEQ + t) * 8 + g) * 128);
                vn[u] = __builtin_nontemporal_load(&vp[col]);
            }
        }
        #pragma unroll
        for (int u = 0; u < 4; ++u) {
            #pragma unroll
            for (int r = 0; r < 4; ++r) {
                const float pr = p_lds[r][wave * 64 + tt * 8 + u * 2 + h];
                a[r][0] = fmaf(pr, vb[u][0], a[r][0]);
                a[r][1] = fmaf(pr, vb[u][1], a[r][1]);
                a[r][2] = fmaf(pr, vb[u][2], a[r][2]);
                a[r][3] = fmaf(pr, vb[u][3], a[r][3]);
            }
        }
        #pragma unroll
        for (int u = 0; u < 4; ++u) vb[u] = vn[u];
    }
    #pragma unroll
    for (int r = 0; r < 4; ++r)
        #pragma unroll
        for (int j = 0; j < 4; ++j) a[r][j] += __shfl_xor(a[r][j], 32);
    if (lane < 32) {
        #pragma unroll
        for (int r = 0; r < 4; ++r) {
            vf4 v; v[0] = a[r][0]; v[1] = a[r][1]; v[2] = a[r][2]; v[3] = a[r][3];
            *(vf4*)&pacc[wave][r][col * 4] = v;
        }
    }
    __syncthreads();
    const size_t base = (size_t)blk * 520;
    for (int o = tid; o < 512; o += 256) {
        const int r = o >> 7, d = o & 127;
        cws[base + r * 130 + d] =
            pacc[0][r][d] + pacc[1][r][d] + pacc[2][r][d] + pacc[3][r][d];
    }
    if (tid == 0) {
        #pragma unroll
        for (int r = 0; r < 4; ++r) {
            cws[base + r * 130 + 128] = M[r];
            cws[base + r * 130 + 129] = S[r];
        }
    }
}

// K3: flash combine over 8 chunks. Grid = 256 (b,g); wave = GQA head.
__global__ __launch_bounds__(256) void k3_comb(const float* __restrict__ cws,
                                               float* __restrict__ attn) {
    const int blk = blockIdx.x;       // b*8 + g
    const int b = blk >> 3, g = blk & 7;
    const int tid = threadIdx.x, r = tid >> 6, lane = tid & 63;
    const size_t base0 = (size_t)blk * 8 * 520 + r * 130;
    float mi[8], si[8];
    float Mg = -3.4e38f;
    #pragma unroll
    for (int ci = 0; ci < 8; ++ci) {
        mi[ci] = cws[base0 + (size_t)ci * 520 + 128];
        si[ci] = cws[base0 + (size_t)ci * 520 + 129];
        Mg = fmaxf(Mg, mi[ci]);
    }
    float w[8], Sg = 0.f;
    #pragma unroll
    for (int ci = 0; ci < 8; ++ci) {
        w[ci] = __expf(mi[ci] - Mg);
        Sg = fmaf(si[ci], w[ci], Sg);
    }
    const float inv = 1.f / Sg;
    #pragma unroll
    for (int dd = 0; dd < 2; ++dd) {
        const int d = lane + dd * 64;
        float o = 0.f;
        #pragma unroll
        for (int ci = 0; ci < 8; ++ci)
            o = fmaf(cws[base0 + (size_t)ci * 520 + d], w[ci], o);
        attn[((size_t)b * 32 + g * 4 + r) * 128 + d] = o * inv;
    }
}

// K4: output projection + atomicAdd into (pre-zeroed) d_out.
// Grid = 32 rowblocks x 16 K-chunks = 512.
__global__ __launch_bounds__(256) void k4_out(
    const float* __restrict__ attn, const float* __restrict__ wo,
    float* __restrict__ out) {
    const int rb = blockIdx.x >> 4, kc = blockIdx.x & 15;
    const int rbase = rb * 128;
    float c[4][4] = {};
    gemm_tile(wo + (size_t)rbase * DIM_, attn, kc * KCH, c);
    const int tid = threadIdx.x;
    const int rg = tid >> 3, bg = tid & 7;
    #pragma unroll
    for (int i = 0; i < 4; ++i) {
        const int row = rbase + rg + 32 * i;
        #pragma unroll
        for (int j = 0; j < 4; ++j)
            atomicAdd(&out[(size_t)(bg + 8 * j) * 4096 + row], c[i][j]);
    }
}

// ---------------------------------------------------------------------------
// Workspace (floats):
//   q_ws: 0         131,072   \
//   k_ws: 131,072    32,768    } zeroed by one memsetAsync (786 KB)
//   v_ws: 163,840    32,768   /
//   cws:  196,608  1,064,960   (fully written by k2)
//   attn: 1,261,568  131,072   => ~5.6 MB total
// d_out zeroed by memsetAsync (k4 accumulates atomically).
// ---------------------------------------------------------------------------
extern "C" void kernel_launch(void* const* d_in, const int* in_sizes, int n_in,
                              void* d_out, int out_size, void* d_ws, size_t ws_size,
                              hipStream_t stream) {
    const float* x    = (const float*)d_in[0];
    const float* wq   = (const float*)d_in[1];
    const float* wk   = (const float*)d_in[2];
    const float* wv   = (const float*)d_in[3];
    const float* wo   = (const float*)d_in[4];
    const float* cK   = (const float*)d_in[5];
    const float* cV   = (const float*)d_in[6];
    const float* fcos = (const float*)d_in[7];
    const float* fsin = (const float*)d_in[8];
    float* ws   = (float*)d_ws;
    float* q_ws = ws;
    float* k_ws = ws + 131072;
    float* v_ws = ws + 163840;
    float* cws  = ws + 196608;
    float* attn = ws + 1261568;
    float* out  = (float*)d_out;

    hipMemsetAsync(q_ws, 0, 196608 * sizeof(float), stream);   // q+k+v region
    hipMemsetAsync(out,  0, (size_t)out_size * sizeof(float), stream);
    hipLaunchKernelGGL(k1_qkv,  dim3(768),  dim3(256), 0, stream,
                       x, wq, wk, wv, fcos, fsin, q_ws, k_ws, v_ws);
    hipLaunchKernelGGL(k2_attn, dim3(2048), dim3(256), 0, stream,
                       q_ws, k_ws, v_ws, cK, cV, cws);
    hipLaunchKernelGGL(k3_comb, dim3(256),  dim3(256), 0, stream, cws, attn);
    hipLaunchKernelGGL(k4_out,  dim3(512),  dim3(256), 0, stream, attn, wo, out);
}